// Round 11
// baseline (230.753 us; speedup 1.0000x reference)
//
#include <hip/hip_runtime.h>

// SSIM loss, fused. R16: fully-private register streaming — ZERO LDS, ZERO
// barriers, ZERO shuffles, ZERO cross-lane exchange.
// Post-mortem chain: R10-R15 refuted occupancy, DS-op count, barrier count,
// and vmcnt-drain theories (all land 84-115us, no pipe >40%, ~6500cy/row vs
// ~800cy issued). Surviving diagnosis: phase-locked convoy — per-row
// barriers (or bpermute chains) keep all co-resident waves in the SAME
// phase, so LDS-latency windows and VALU windows SUM instead of overlap.
// R16 removes the exchange: each lane owns 4 adjacent output cols and loads
// its own 14-col window (5 aligned float4/img, neighbor overlap served by
// L1), computes the 11-tap horizontal sums in registers via a 14-prefix,
// and keeps the vertical running window Wt[4][4] in registers (add row
// r+6 / sub row r-5 per advance).
//  - u=x+y, v=x-y -> 4 channels (Su,Sv,Suu,Svv), same SSIM algebra.
//  - add-row PREFETCHED one iteration ahead (full-iteration cover);
//    sub-row is an L2/L3-hot re-read issued before the SSIM math.
//  - image edges: clamped load bases + per-lane validity masks (fA..fE).
//  - 2048 blocks x 128 thr (the empirically-best block size), STRIP=16.

#define IMG_H 512
#define IMG_W 512
#define N_IMG 64
#define STRIP 16           // output rows per block -> grid (32,64)=2048 blocks
#define NTHREADS 128       // 2 independent waves; lane owns 4 cols

__global__ __launch_bounds__(NTHREADS, 2) void ssim_kernel(const float* __restrict__ img1,
                                                           const float* __restrict__ img2,
                                                           float* __restrict__ ws) {
    const int t = threadIdx.x;                   // 0..127
    const int b = blockIdx.y;
    const int r0 = blockIdx.x * STRIP;
    const float* __restrict__ p1 = img1 + (size_t)b * (IMG_H * IMG_W);
    const float* __restrict__ p2 = img2 + (size_t)b * (IMG_H * IMG_W);
    const int c4 = 4 * t;                        // owns cols c4..c4+3

    // Clamped, 16B-aligned load bases for the 14-col window [c4-5, c4+8],
    // plus validity masks for the out-of-image elements.
    const int oA = (c4 - 8 > 0) ? c4 - 8 : 0;    // A.w   = col c4-5
    const int oB = (c4 - 4 > 0) ? c4 - 4 : 0;    // B.xyzw= cols c4-4..c4-1
    const int oC = c4;                           // C     = cols c4..c4+3
    const int oD = (c4 + 4 < 508) ? c4 + 4 : 508;// D     = cols c4+4..c4+7
    const int oE = (c4 + 8 < 508) ? c4 + 8 : 508;// E.x   = col c4+8
    const float fA = (c4 - 5 >= 0) ? 1.0f : 0.0f;
    const float fB = (c4 - 4 >= 0) ? 1.0f : 0.0f;
    const float fD = (c4 + 7 <= IMG_W - 1) ? 1.0f : 0.0f;
    const float fE = (c4 + 8 <= IMG_W - 1) ? 1.0f : 0.0f;

    struct Row { float4 A1, B1, C1, D1, E1, A2, B2, C2, D2, E2; };
    auto issueRow = [&](int r, Row& R) {
        const float* q1 = p1 + (size_t)r * IMG_W;
        const float* q2 = p2 + (size_t)r * IMG_W;
        R.A1 = *(const float4*)(q1 + oA); R.B1 = *(const float4*)(q1 + oB);
        R.C1 = *(const float4*)(q1 + oC); R.D1 = *(const float4*)(q1 + oD);
        R.E1 = *(const float4*)(q1 + oE);
        R.A2 = *(const float4*)(q2 + oA); R.B2 = *(const float4*)(q2 + oB);
        R.C2 = *(const float4*)(q2 + oC); R.D2 = *(const float4*)(q2 + oD);
        R.E2 = *(const float4*)(q2 + oE);
    };

    float Wt[4][4];                              // ch(u,v,uu,vv) x 4 px
#pragma unroll
    for (int ch = 0; ch < 4; ++ch)
#pragma unroll
        for (int j = 0; j < 4; ++j) Wt[ch][j] = 0.0f;

    // Add/sub one image row's 11-tap horizontal sums into Wt (sgn = +-1).
    auto applyRow = [&](const Row& R, const float sgn) {
        float xs[14], ys[14];
        xs[0] = R.A1.w * fA;
        xs[1] = R.B1.x * fB; xs[2] = R.B1.y * fB; xs[3] = R.B1.z * fB; xs[4] = R.B1.w * fB;
        xs[5] = R.C1.x;      xs[6] = R.C1.y;      xs[7] = R.C1.z;      xs[8] = R.C1.w;
        xs[9] = R.D1.x * fD; xs[10] = R.D1.y * fD; xs[11] = R.D1.z * fD; xs[12] = R.D1.w * fD;
        xs[13] = R.E1.x * fE;
        ys[0] = R.A2.w * fA;
        ys[1] = R.B2.x * fB; ys[2] = R.B2.y * fB; ys[3] = R.B2.z * fB; ys[4] = R.B2.w * fB;
        ys[5] = R.C2.x;      ys[6] = R.C2.y;      ys[7] = R.C2.z;      ys[8] = R.C2.w;
        ys[9] = R.D2.x * fD; ys[10] = R.D2.y * fD; ys[11] = R.D2.z * fD; ys[12] = R.D2.w * fD;
        ys[13] = R.E2.x * fE;
        float u[14], v[14];
#pragma unroll
        for (int k = 0; k < 14; ++k) { u[k] = xs[k] + ys[k]; v[k] = xs[k] - ys[k]; }
        float pu[14], pv[14], puu[14], pvv[14];
        pu[0] = u[0]; pv[0] = v[0];
        puu[0] = u[0] * u[0]; pvv[0] = v[0] * v[0];
#pragma unroll
        for (int k = 1; k < 14; ++k) {
            pu[k] = pu[k - 1] + u[k];
            pv[k] = pv[k - 1] + v[k];
            puu[k] = fmaf(u[k], u[k], puu[k - 1]);
            pvv[k] = fmaf(v[k], v[k], pvv[k - 1]);
        }
#pragma unroll
        for (int j = 0; j < 4; ++j) {
            const float w0 = (j == 0) ? pu[10]  : pu[j + 10]  - pu[j - 1];
            const float w1 = (j == 0) ? pv[10]  : pv[j + 10]  - pv[j - 1];
            const float w2 = (j == 0) ? puu[10] : puu[j + 10] - puu[j - 1];
            const float w3 = (j == 0) ? pvv[10] : pvv[j + 10] - pvv[j - 1];
            Wt[0][j] = fmaf(sgn, w0, Wt[0][j]);
            Wt[1][j] = fmaf(sgn, w1, Wt[1][j]);
            Wt[2][j] = fmaf(sgn, w2, Wt[2][j]);
            Wt[3][j] = fmaf(sgn, w3, Wt[3][j]);
        }
    };

    // Warm the vertical window for output row r0 (rows r0-5..r0+5, clamped).
    {
        int rlo = r0 - 5; if (rlo < 0) rlo = 0;
        const int rhi = r0 + 5;                  // r0 <= 496 -> rhi <= 501
        for (int r = rlo; r <= rhi; ++r) {
            Row R; issueRow(r, R); applyRow(R, 1.0f);
        }
    }

    constexpr float inv  = 1.0f / 121.0f;
    constexpr float inv2 = 0.5f / 121.0f;
    constexpr float C1c = 0.01f * 0.01f;
    constexpr float C2c = 0.03f * 0.03f;
    float acc = 0.0f;

    // Prefetch the first advance's add-row (row r0+6; clamped redundant).
    Row nextAdd;
    { int ra = r0 + 6; if (ra > IMG_H - 1) ra = IMG_H - 1; issueRow(ra, nextAdd); }

    for (int i = 0; i < STRIP; ++i) {
        const int r = r0 + i;
        const bool lastIt = (i == STRIP - 1);

        // Sub-row (r-5): L2/L3-hot re-read (first touched 11 rows ago).
        // Issue before the SSIM math so its latency is covered.
        Row subR;
        const bool doSub = !lastIt && (r - 5 >= 0);            // block-uniform
        if (doSub) issueRow(r - 5, subR);

        // --- SSIM for the 4 px this lane owns in row r ---
#pragma unroll
        for (int j = 0; j < 4; ++j) {
            float mu_u = Wt[0][j] * inv, mu_v = Wt[1][j] * inv;
            float uu = mu_u * mu_u, vv = mu_v * mu_v;
            float P = 0.5f * (uu + vv);                  // mu1^2 + mu2^2
            float M = 0.5f * (uu - vv);                  // 2*mu1*mu2
            float A = fmaf(Wt[2][j] + Wt[3][j], inv2, -P);  // sig1^2+sig2^2
            float B = fmaf(Wt[2][j] - Wt[3][j], inv2, -M);  // 2*sig12
            acc += __fdividef((M + C1c) * (B + C2c), (P + C1c) * (A + C2c));
        }

        // --- advance Wt to row r+1: add r+6 (prefetched), sub r-5 ---
        if (!lastIt) {
            if (r + 6 <= IMG_H - 1) applyRow(nextAdd, 1.0f);   // vmcnt: 1 iter cover
            if (i < STRIP - 2) {                               // prefetch next add
                int ra = r + 7; if (ra > IMG_H - 1) ra = IMG_H - 1;
                issueRow(ra, nextAdd);
            }
            if (doSub) applyRow(subR, -1.0f);
        }
    }

    // Reduce: intra-wave shuffle tree -> one atomic per wave (no LDS).
#pragma unroll
    for (int off = 32; off > 0; off >>= 1) acc += __shfl_down(acc, off);
    if ((t & 63) == 0) atomicAdd(ws, acc);
}

__global__ void ssim_finalize(const float* __restrict__ ws, float* __restrict__ out) {
    constexpr float inv_n = 1.0f / (float)((size_t)N_IMG * IMG_H * IMG_W);
    out[0] = 1.0f - ws[0] * inv_n;
}

extern "C" void kernel_launch(void* const* d_in, const int* in_sizes, int n_in,
                              void* d_out, int out_size, void* d_ws, size_t ws_size,
                              hipStream_t stream) {
    const float* img1 = (const float*)d_in[0];
    const float* img2 = (const float*)d_in[1];
    float* out = (float*)d_out;
    float* ws = (float*)d_ws;

    hipMemsetAsync(ws, 0, sizeof(float), stream);

    dim3 grid(IMG_H / STRIP, N_IMG);   // (32, 64) = 2048 blocks, 128 thr
    ssim_kernel<<<grid, NTHREADS, 0, stream>>>(img1, img2, ws);
    ssim_finalize<<<1, 1, 0, stream>>>(ws, out);
}